// Round 15
// baseline (522.720 us; speedup 1.0000x reference)
//
#include <hip/hip_runtime.h>
#include <hip/hip_bf16.h>

#define N_NODES   50000
#define N_EDGES   600000
#define HID       128
#define N_LAYERS  4
#define N_GRAPHS  128
#define N_CLASSES 10
#define BN_EPS    1e-5f

#define RSPLIT 8
#define GEMM_GRID ((N_NODES + 63) / 64)   // 782
#define CVT_N   3200000
#define CVT_GRID ((CVT_N + 255) / 256)
#define NREP 32             // colsum replica banks
#define ELL_W 64            // max degree slots (Poisson(12): P(>=64) < 1e-26)

// ---------------- workspace layout (in 4-byte elements) ----------------
#define OFF_WMT   0u                         // 5 x [2][128][64] u32 bf16-pairs = 81920
#define OFF_H     81920u                     // 50000*128 fp32
#define OFF_Z     (OFF_H + 6400000u)
#define OFF_H0BF  (OFF_Z + 6400000u)         // [50000][64] u32 bf16 h0
#define OFF_ZERO  (OFF_H0BF + 3200000u)
#define OFF_CSUMR OFF_ZERO                   // [4][32][256] = 32768
#define OFF_SUMS  (OFF_CSUMR + 32768u)       // [128][128] = 16384
#define OFF_DEG   (OFF_SUMS + 16384u)        // [50000]
#define ZERO_N    (32768u + 16384u + 50000u) // 99152
#define OFF_ELL   (OFF_ZERO + ZERO_N)        // [50000][64] int = 3200000
#define OFF_GST   (OFF_ELL + 3200000u)       // [129] (pad 132)
#define OFF_CSUMF (OFF_GST + 132u)           // [4][2][128] = 1024
#define OFF_HBF   (OFF_CSUMF + 1024u)        // [50000][64] u32 bf16 H

// preamble block ranges
#define PRE_ZB 388                    // 99152 -> 388*256
#define PRE_WB 160                    // 5*128*64 = 40960 threads
#define PRE_BB 196

typedef __attribute__((ext_vector_type(8))) short short8;
typedef __attribute__((ext_vector_type(4))) float f32x4;

// bf16 helpers (RNE)
__device__ __forceinline__ unsigned int bf16_of(float f) {
    unsigned int u = __float_as_uint(f);
    return (u + 0x7fffu + ((u >> 16) & 1u)) >> 16;
}
__device__ __forceinline__ unsigned int pack_bf2(float lo, float hi) {
    return bf16_of(lo) | (bf16_of(hi) << 16);
}

// fused preamble: zero | masked W -> bf16 split-pair [p][c][k] | graph bounds
__global__ __launch_bounds__(256) void preamble_kernel(
    int* __restrict__ zbase,
    const float* __restrict__ We, const float* __restrict__ Me,
    const float* __restrict__ Wl, const float* __restrict__ Ml,
    unsigned int* __restrict__ Wbf,
    const int* __restrict__ gid, int* __restrict__ g_start)
{
    int b = blockIdx.x;
    if (b < PRE_ZB) {
        int i = b * 256 + threadIdx.x;
        if (i < (int)ZERO_N) zbase[i] = 0;
    } else if (b < PRE_ZB + PRE_WB) {
        int i = (b - PRE_ZB) * 256 + threadIdx.x;
        if (i < 5 * 8192) {
            int m = i >> 13;
            int j = i & 8191;
            int c = j >> 6, ku = j & 63;
            const float* Wsrc = (m == 0) ? We : Wl + (m - 1) * 16384;
            const float* Msrc = (m == 0) ? Me : Ml + (m - 1) * 16384;
            int base = c * 128 + ku * 2;
            float w0 = Wsrc[base] * Msrc[base];
            float w1 = Wsrc[base + 1] * Msrc[base + 1];
            unsigned int h0 = bf16_of(w0), h1 = bf16_of(w1);
            float l0 = w0 - __uint_as_float(h0 << 16);
            float l1 = w1 - __uint_as_float(h1 << 16);
            Wbf[m * 16384 + c * 64 + ku]        = h0 | (h1 << 16);
            Wbf[m * 16384 + 8192 + c * 64 + ku] = bf16_of(l0) | (bf16_of(l1) << 16);
        }
    } else {
        int i = (b - PRE_ZB - PRE_WB) * 256 + threadIdx.x;
        if (i >= N_NODES) return;
        int g = gid[i];
        if (i == 0) {
            for (int x = 0; x <= g; ++x) g_start[x] = 0;
        } else {
            int gp = gid[i - 1];
            for (int x = gp + 1; x <= g; ++x) g_start[x] = i;
        }
        if (i == N_NODES - 1) {
            for (int x = g + 1; x <= N_GRAPHS; ++x) g_start[x] = N_NODES;
        }
    }
}

// ELL build: deg[dst]++ slots, ell[dst*ELL_W + slot] = src  (replaces hist+scan+fill)
__global__ __launch_bounds__(256) void ellfill_kernel(const int* __restrict__ src,
                                                      const int* __restrict__ dst,
                                                      int* __restrict__ deg,
                                                      int* __restrict__ ell, int nE) {
    int i = blockIdx.x * 256 + threadIdx.x;
    if (i < nE) {
        int d = dst[i];
        int slot = atomicAdd(&deg[d], 1);
        if (slot < ELL_W) ell[(size_t)d * ELL_W + slot] = src[i];
    }
}

// fp32 pairs -> packed bf16 u32
__global__ __launch_bounds__(256) void cvt_kernel(const float2* __restrict__ src,
                                                  unsigned int* __restrict__ dst, int n) {
    int i = blockIdx.x * 256 + threadIdx.x;
    if (i < n) {
        float2 v = src[i];
        dst[i] = pack_bf2(v.x, v.y);
    }
}

// dense MFMA GEMM for the embedding layer; writes H (fp32) and Hbf (bf16 ushorts)
__global__ __launch_bounds__(256) void gemm_mfma(
    const uint4* __restrict__ Abf,
    const unsigned int* __restrict__ Wmat,
    const float* __restrict__ bias,
    float* __restrict__ Z, unsigned int* __restrict__ hbf, int nRows)
{
    __shared__ unsigned int As[64 * 64];
    int tid = threadIdx.x;
    int w  = tid >> 6;
    int l  = tid & 63;
    int q  = l >> 4;
    int ri = l & 15;
    int r0 = blockIdx.x * 64;

    short8 bfrag[2][2][4];
    const uint4* W4 = (const uint4*)Wmat;
#pragma unroll
    for (int p = 0; p < 2; ++p)
#pragma unroll
        for (int ct2 = 0; ct2 < 2; ++ct2) {
            int c = (w * 2 + ct2) * 16 + ri;
#pragma unroll
            for (int kc = 0; kc < 4; ++kc) {
                uint4 t = W4[p * 2048 + c * 16 + kc * 4 + q];
                bfrag[p][ct2][kc] = *(short8*)&t;
            }
        }

#pragma unroll
    for (int it = 0; it < 4; ++it) {
        int e = tid + it * 256;
        int r = e >> 4, g = e & 15;
        int gr = r0 + r;
        if (gr >= nRows) gr = nRows - 1;
        uint4 v = Abf[(size_t)gr * 16 + g];
        *(uint4*)&As[r * 64 + ((g ^ (r & 7)) << 2)] = v;
    }
    __syncthreads();

    f32x4 zero4 = {0.f, 0.f, 0.f, 0.f};
    f32x4 acc[4][2];
#pragma unroll
    for (int rt = 0; rt < 4; ++rt)
#pragma unroll
        for (int ct2 = 0; ct2 < 2; ++ct2) acc[rt][ct2] = zero4;

#pragma unroll
    for (int kc = 0; kc < 4; ++kc)
#pragma unroll
        for (int rt = 0; rt < 4; ++rt) {
            int row = rt * 16 + ri;
            short8 af = *(const short8*)&As[row * 64 + (((kc * 4 + q) ^ (ri & 7)) << 2)];
#pragma unroll
            for (int ct2 = 0; ct2 < 2; ++ct2) {
                acc[rt][ct2] = __builtin_amdgcn_mfma_f32_16x16x32_bf16(
                    af, bfrag[0][ct2][kc], acc[rt][ct2], 0, 0, 0);
                acc[rt][ct2] = __builtin_amdgcn_mfma_f32_16x16x32_bf16(
                    af, bfrag[1][ct2][kc], acc[rt][ct2], 0, 0, 0);
            }
        }

    unsigned short* hb = (unsigned short*)hbf;
#pragma unroll
    for (int ct2 = 0; ct2 < 2; ++ct2) {
        int col = (w * 2 + ct2) * 16 + ri;
        float bb = bias[col];
#pragma unroll
        for (int rt = 0; rt < 4; ++rt)
#pragma unroll
            for (int reg = 0; reg < 4; ++reg) {
                int row = r0 + rt * 16 + q * 4 + reg;
                if (row < nRows) {
                    float v = acc[rt][ct2][reg] + bb;
                    Z[(size_t)row * 128 + col] = v;
                    hb[(size_t)row * 128 + col] = (unsigned short)bf16_of(v);
                }
            }
    }
}

// FUSED: gather-aggregate 64 node rows (ELL edges, bf16 H, fp32 accum) directly
// into the swizzled LDS A-tile, then MFMA vs split-pair W, epilogue snorm+colsum.
__global__ __launch_bounds__(256) void agg_gemm_mfma(
    const unsigned int* __restrict__ Hbf,
    const int* __restrict__ deg, const int* __restrict__ ell,
    const unsigned int* __restrict__ Wmat,
    const float* __restrict__ bias, const float* __restrict__ snorm,
    float* __restrict__ Z, float* __restrict__ colsum, int nRows)
{
    __shared__ unsigned int As[64 * 64];  // 16 KB
    int tid = threadIdx.x;
    int w  = tid >> 6;
    int l  = tid & 63;
    int q  = l >> 4;
    int ri = l & 15;
    int half = l >> 5;
    int l4   = l & 31;
    int r0 = blockIdx.x * 64;

    // ---- gather phase: 8 iters x 2 nodes/wave, unroll x8 (16 streams/wave) ----
    const uint2* H2 = (const uint2*)Hbf;
#pragma unroll
    for (int iter = 0; iter < 8; ++iter) {
        int rl = iter * 8 + w * 2 + half;          // local row 0..63
        int node = r0 + rl;
        if (node >= nRows) node = nRows - 1;
        int dg = deg[node];
        const int* ep = ell + (size_t)node * ELL_W;
        float4 a0 = make_float4(0.f, 0.f, 0.f, 0.f);
        float4 a1 = make_float4(0.f, 0.f, 0.f, 0.f);
        float4 a2 = make_float4(0.f, 0.f, 0.f, 0.f);
        float4 a3 = make_float4(0.f, 0.f, 0.f, 0.f);
#define ACCUM(AX, V)                                                        \
        AX.x += __uint_as_float((V).x << 16);                               \
        AX.y += __uint_as_float((V).x & 0xffff0000u);                       \
        AX.z += __uint_as_float((V).y << 16);                               \
        AX.w += __uint_as_float((V).y & 0xffff0000u);
        int e = 0;
        for (; e + 7 < dg; e += 8) {
            int s0 = ep[e],     s1 = ep[e + 1], s2 = ep[e + 2], s3 = ep[e + 3];
            int s4 = ep[e + 4], s5 = ep[e + 5], s6 = ep[e + 6], s7 = ep[e + 7];
            uint2 v0 = H2[(size_t)s0 * 32 + l4];
            uint2 v1 = H2[(size_t)s1 * 32 + l4];
            uint2 v2 = H2[(size_t)s2 * 32 + l4];
            uint2 v3 = H2[(size_t)s3 * 32 + l4];
            uint2 v4 = H2[(size_t)s4 * 32 + l4];
            uint2 v5 = H2[(size_t)s5 * 32 + l4];
            uint2 v6 = H2[(size_t)s6 * 32 + l4];
            uint2 v7 = H2[(size_t)s7 * 32 + l4];
            ACCUM(a0, v0) ACCUM(a1, v1) ACCUM(a2, v2) ACCUM(a3, v3)
            ACCUM(a0, v4) ACCUM(a1, v5) ACCUM(a2, v6) ACCUM(a3, v7)
        }
        for (; e + 3 < dg; e += 4) {
            int s0 = ep[e], s1 = ep[e + 1], s2 = ep[e + 2], s3 = ep[e + 3];
            uint2 v0 = H2[(size_t)s0 * 32 + l4];
            uint2 v1 = H2[(size_t)s1 * 32 + l4];
            uint2 v2 = H2[(size_t)s2 * 32 + l4];
            uint2 v3 = H2[(size_t)s3 * 32 + l4];
            ACCUM(a0, v0) ACCUM(a1, v1) ACCUM(a2, v2) ACCUM(a3, v3)
        }
        for (; e < dg; ++e) {
            uint2 v0 = H2[(size_t)ep[e] * 32 + l4];
            ACCUM(a0, v0)
        }
#undef ACCUM
        a0.x += a1.x; a0.y += a1.y; a0.z += a1.z; a0.w += a1.w;
        a2.x += a3.x; a2.y += a3.y; a2.z += a3.z; a2.w += a3.w;
        a0.x += a2.x; a0.y += a2.y; a0.z += a2.z; a0.w += a2.w;
        // pack to bf16 and store into swizzled A-tile: cols l4*4..l4*4+3
        uint2 o;
        o.x = pack_bf2(a0.x, a0.y);
        o.y = pack_bf2(a0.z, a0.w);
        int g16 = l4 >> 1;
        *(uint2*)&As[rl * 64 + ((g16 ^ (rl & 7)) << 2) + (l4 & 1) * 2] = o;
    }

    // ---- B fragments (L2-resident; loaded after gather to cap VGPR pressure) ----
    short8 bfrag[2][2][4];
    const uint4* W4 = (const uint4*)Wmat;
#pragma unroll
    for (int p = 0; p < 2; ++p)
#pragma unroll
        for (int ct2 = 0; ct2 < 2; ++ct2) {
            int c = (w * 2 + ct2) * 16 + ri;
#pragma unroll
            for (int kc = 0; kc < 4; ++kc) {
                uint4 t = W4[p * 2048 + c * 16 + kc * 4 + q];
                bfrag[p][ct2][kc] = *(short8*)&t;
            }
        }
    __syncthreads();

    // ---- MFMA phase ----
    f32x4 zero4 = {0.f, 0.f, 0.f, 0.f};
    f32x4 acc[4][2];
#pragma unroll
    for (int rt = 0; rt < 4; ++rt)
#pragma unroll
        for (int ct2 = 0; ct2 < 2; ++ct2) acc[rt][ct2] = zero4;

#pragma unroll
    for (int kc = 0; kc < 4; ++kc)
#pragma unroll
        for (int rt = 0; rt < 4; ++rt) {
            int row = rt * 16 + ri;
            short8 af = *(const short8*)&As[row * 64 + (((kc * 4 + q) ^ (ri & 7)) << 2)];
#pragma unroll
            for (int ct2 = 0; ct2 < 2; ++ct2) {
                acc[rt][ct2] = __builtin_amdgcn_mfma_f32_16x16x32_bf16(
                    af, bfrag[0][ct2][kc], acc[rt][ct2], 0, 0, 0);
                acc[rt][ct2] = __builtin_amdgcn_mfma_f32_16x16x32_bf16(
                    af, bfrag[1][ct2][kc], acc[rt][ct2], 0, 0, 0);
            }
        }

    // ---- epilogue: bias, snorm, Z store, replica colsum ----
    float csv[2] = {0.f, 0.f}, cqv[2] = {0.f, 0.f};
#pragma unroll
    for (int ct2 = 0; ct2 < 2; ++ct2) {
        int col = (w * 2 + ct2) * 16 + ri;
        float bb = bias[col];
#pragma unroll
        for (int rt = 0; rt < 4; ++rt)
#pragma unroll
            for (int reg = 0; reg < 4; ++reg) {
                int row = r0 + rt * 16 + q * 4 + reg;
                if (row < nRows) {
                    float sn = snorm[row];
                    float v = (acc[rt][ct2][reg] + bb) * sn;
                    Z[(size_t)row * 128 + col] = v;
                    csv[ct2] += v;
                    cqv[ct2] += v * v;
                }
            }
    }
    {
        float* cdst = colsum + ((blockIdx.x & (NREP - 1)) << 8);
#pragma unroll
        for (int ct2 = 0; ct2 < 2; ++ct2) {
            float s  = csv[ct2], sq = cqv[ct2];
            s  += __shfl_xor(s, 16);  s  += __shfl_xor(s, 32);
            sq += __shfl_xor(sq, 16); sq += __shfl_xor(sq, 32);
            if (q == 0) {
                int col = (w * 2 + ct2) * 16 + ri;
                atomicAdd(&cdst[col], s);
                atomicAdd(&cdst[128 + col], sq);
            }
        }
    }
}

// fold NREP replica banks -> final csum[256] for one layer
__global__ __launch_bounds__(256) void bnred_kernel(const float* __restrict__ rep,
                                                    float* __restrict__ outp) {
    int t = threadIdx.x;
    float s = 0.f;
#pragma unroll
    for (int r = 0; r < NREP; ++r) s += rep[r * 256 + t];
    outp[t] = s;
}

// H += relu(BN(Z)); also emit bf16 H copy for the next layer's gather
__global__ __launch_bounds__(256) void apply_kernel(const float* __restrict__ Z,
                                                    const float* __restrict__ csum,
                                                    const float* __restrict__ gamma,
                                                    const float* __restrict__ beta,
                                                    float* __restrict__ H,
                                                    unsigned int* __restrict__ hbf,
                                                    int n4, int layer) {
    int i = blockIdx.x * 256 + threadIdx.x;
    if (i >= n4) return;
    int c4 = i & 31;
    const float invN = 1.0f / (float)N_NODES;
    float4 s  = ((const float4*)(csum  + layer * 256))[c4];
    float4 q  = ((const float4*)(csum  + layer * 256 + 128))[c4];
    float4 g  = ((const float4*)(gamma + layer * 128))[c4];
    float4 be = ((const float4*)(beta  + layer * 128))[c4];
    float4 z = ((const float4*)Z)[i];
    float4 h = ((float4*)H)[i];
    float mu, var, sc, sh;
    mu = s.x * invN; var = q.x * invN - mu * mu; sc = g.x * rsqrtf(var + BN_EPS); sh = be.x - mu * sc;
    h.x += fmaxf(z.x * sc + sh, 0.f);
    mu = s.y * invN; var = q.y * invN - mu * mu; sc = g.y * rsqrtf(var + BN_EPS); sh = be.y - mu * sc;
    h.y += fmaxf(z.y * sc + sh, 0.f);
    mu = s.z * invN; var = q.z * invN - mu * mu; sc = g.z * rsqrtf(var + BN_EPS); sh = be.z - mu * sc;
    h.z += fmaxf(z.z * sc + sh, 0.f);
    mu = s.w * invN; var = q.w * invN - mu * mu; sc = g.w * rsqrtf(var + BN_EPS); sh = be.w - mu * sc;
    h.w += fmaxf(z.w * sc + sh, 0.f);
    ((float4*)H)[i] = h;
    hbf[i * 2]     = pack_bf2(h.x, h.y);
    hbf[i * 2 + 1] = pack_bf2(h.z, h.w);
}

// dense per-graph reduction using sorted-gid boundaries (fp32 H)
__global__ __launch_bounds__(256) void readout2_kernel(const float* __restrict__ H,
                                                       const int* __restrict__ g_start,
                                                       float* __restrict__ sums) {
    int g     = blockIdx.x / RSPLIT;
    int chunk = blockIdx.x % RSPLIT;
    int beg = g_start[g], end = g_start[g + 1];
    int col  = threadIdx.x & 127;
    int half = threadIdx.x >> 7;
    float acc = 0.f;
    for (int r = beg + chunk * 2 + half; r < end; r += RSPLIT * 2) {
        acc += H[(size_t)r * 128 + col];
    }
    if (acc != 0.f || half == 0)
        atomicAdd(&sums[g * 128 + col], acc);
}

__global__ __launch_bounds__(128) void final_kernel(const float* __restrict__ sums,
                                                    const int* __restrict__ g_start,
                                                    const float* __restrict__ roW,
                                                    const float* __restrict__ rob,
                                                    float* __restrict__ out) {
    __shared__ float row[128];
    int g = blockIdx.x;
    int t = threadIdx.x;
    float c = fmaxf((float)(g_start[g + 1] - g_start[g]), 1.0f);
    row[t] = sums[g * 128 + t] / c;
    __syncthreads();
    if (t < N_CLASSES) {
        float s = rob[t];
        for (int k = 0; k < 128; ++k) s += row[k] * roW[t * 128 + k];
        out[g * N_CLASSES + t] = s;
    }
}

extern "C" void kernel_launch(void* const* d_in, const int* in_sizes, int n_in,
                              void* d_out, int out_size, void* d_ws, size_t ws_size,
                              hipStream_t stream) {
    const float* h0      = (const float*)d_in[0];
    const float* snorm   = (const float*)d_in[1];
    const int*   src     = (const int*)d_in[2];
    const int*   dst     = (const int*)d_in[3];
    const int*   gid     = (const int*)d_in[4];
    const float* embedW  = (const float*)d_in[5];
    const float* embedM  = (const float*)d_in[6];
    const float* embedB  = (const float*)d_in[7];
    const float* layerW  = (const float*)d_in[8];
    const float* layerM  = (const float*)d_in[9];
    const float* layerB  = (const float*)d_in[10];
    const float* gamma   = (const float*)d_in[11];
    const float* beta    = (const float*)d_in[12];
    const float* roW     = (const float*)d_in[13];
    const float* rob     = (const float*)d_in[14];
    float* out = (float*)d_out;

    float* ws   = (float*)d_ws;
    unsigned int* Wbf = (unsigned int*)(ws + OFF_WMT);
    float* H    = ws + OFF_H;
    float* Z    = ws + OFF_Z;
    unsigned int* h0bf = (unsigned int*)(ws + OFF_H0BF);
    float* csumr = ws + OFF_CSUMR;
    float* csumf = ws + OFF_CSUMF;
    float* sums = ws + OFF_SUMS;
    int*   deg  = (int*)(ws + OFF_DEG);
    int*   ell  = (int*)(ws + OFF_ELL);
    int*   gst  = (int*)(ws + OFF_GST);
    unsigned int* Hbf = (unsigned int*)(ws + OFF_HBF);

    // preamble: zero (csumr/sums/deg) | W->bf16 split-pair | bounds
    preamble_kernel<<<PRE_ZB + PRE_WB + PRE_BB, 256, 0, stream>>>(
        (int*)(ws + OFF_ZERO), embedW, embedM, layerW, layerM, Wbf, gid, gst);
    // ELL edge lists (replaces hist+scan x3+fill)
    ellfill_kernel<<<(N_EDGES + 255) / 256, 256, 0, stream>>>(src, dst, deg, ell, N_EDGES);

    // h0 -> bf16, embed GEMM (MFMA) -> H fp32 + Hbf bf16
    cvt_kernel<<<CVT_GRID, 256, 0, stream>>>((const float2*)h0, h0bf, CVT_N);
    gemm_mfma<<<GEMM_GRID, 256, 0, stream>>>((const uint4*)h0bf, Wbf, embedB,
                                             H, Hbf, N_NODES);

    for (int l = 0; l < N_LAYERS; ++l) {
        agg_gemm_mfma<<<GEMM_GRID, 256, 0, stream>>>(
            Hbf, deg, ell, Wbf + (1 + l) * 16384,
            layerB + l * 128, snorm, Z, csumr + l * (NREP * 256), N_NODES);
        bnred_kernel<<<1, 256, 0, stream>>>(csumr + l * (NREP * 256), csumf + l * 256);
        apply_kernel<<<(N_NODES * HID / 4) / 256, 256, 0, stream>>>(
            Z, csumf, gamma, beta, H, Hbf, N_NODES * HID / 4, l);
    }

    readout2_kernel<<<N_GRAPHS * RSPLIT, 256, 0, stream>>>(H, gst, sums);
    final_kernel<<<N_GRAPHS, 128, 0, stream>>>(sums, gst, roW, rob, out);
}

// Round 16
// 442.926 us; speedup vs baseline: 1.1802x; 1.1802x over previous
//
#include <hip/hip_runtime.h>
#include <hip/hip_bf16.h>

#define N_NODES   50000
#define N_EDGES   600000
#define HID       128
#define N_LAYERS  4
#define N_GRAPHS  128
#define N_CLASSES 10
#define BN_EPS    1e-5f

#define RSPLIT 8
#define GEMM_GRID ((N_NODES + 63) / 64)   // 782
#define CVT_N   3200000
#define CVT_GRID ((CVT_N + 255) / 256)
#define NREP 32             // colsum replica banks
#define ELL_W 64            // max degree slots (Poisson(12): P(>=64) < 1e-26)

// ---------------- workspace layout (in 4-byte elements) ----------------
#define OFF_WMT   0u                         // 5 x [2][128][64] u32 bf16-pairs = 81920
#define OFF_H     81920u                     // 50000*128 fp32
#define OFF_Z     (OFF_H + 6400000u)
#define OFF_H0BF  (OFF_Z + 6400000u)         // [50000][64] u32 bf16 h0
#define OFF_AGGBF (OFF_H0BF + 3200000u)      // [50000][64] u32 bf16 agg
#define OFF_ZERO  (OFF_AGGBF + 3200000u)
#define OFF_CSUMR OFF_ZERO                   // [4][32][256] = 32768
#define OFF_SUMS  (OFF_CSUMR + 32768u)       // [128][128] = 16384
#define OFF_DEG   (OFF_SUMS + 16384u)        // [50000]
#define ZERO_N    (32768u + 16384u + 50000u) // 99152
#define OFF_ELL   (OFF_ZERO + ZERO_N)        // [50000][64] int = 3200000
#define OFF_GST   (OFF_ELL + 3200000u)       // [129] (pad 132)
#define OFF_CSUMF (OFF_GST + 132u)           // [4][2][128] = 1024
#define OFF_HBF   (OFF_CSUMF + 1024u)        // [50000][64] u32 bf16 H

// preamble block ranges
#define PRE_ZB 388                    // 99152 -> 388*256
#define PRE_WB 160                    // 5*128*64 = 40960 threads
#define PRE_BB 196

typedef __attribute__((ext_vector_type(8))) short short8;
typedef __attribute__((ext_vector_type(4))) float f32x4;

// bf16 helpers (RNE)
__device__ __forceinline__ unsigned int bf16_of(float f) {
    unsigned int u = __float_as_uint(f);
    return (u + 0x7fffu + ((u >> 16) & 1u)) >> 16;
}
__device__ __forceinline__ unsigned int pack_bf2(float lo, float hi) {
    return bf16_of(lo) | (bf16_of(hi) << 16);
}

// fused preamble: zero | masked W -> bf16 split-pair [p][c][k] | graph bounds
__global__ __launch_bounds__(256) void preamble_kernel(
    int* __restrict__ zbase,
    const float* __restrict__ We, const float* __restrict__ Me,
    const float* __restrict__ Wl, const float* __restrict__ Ml,
    unsigned int* __restrict__ Wbf,
    const int* __restrict__ gid, int* __restrict__ g_start)
{
    int b = blockIdx.x;
    if (b < PRE_ZB) {
        int i = b * 256 + threadIdx.x;
        if (i < (int)ZERO_N) zbase[i] = 0;
    } else if (b < PRE_ZB + PRE_WB) {
        int i = (b - PRE_ZB) * 256 + threadIdx.x;
        if (i < 5 * 8192) {
            int m = i >> 13;
            int j = i & 8191;
            int c = j >> 6, ku = j & 63;
            const float* Wsrc = (m == 0) ? We : Wl + (m - 1) * 16384;
            const float* Msrc = (m == 0) ? Me : Ml + (m - 1) * 16384;
            int base = c * 128 + ku * 2;
            float w0 = Wsrc[base] * Msrc[base];
            float w1 = Wsrc[base + 1] * Msrc[base + 1];
            unsigned int h0 = bf16_of(w0), h1 = bf16_of(w1);
            float l0 = w0 - __uint_as_float(h0 << 16);
            float l1 = w1 - __uint_as_float(h1 << 16);
            Wbf[m * 16384 + c * 64 + ku]        = h0 | (h1 << 16);
            Wbf[m * 16384 + 8192 + c * 64 + ku] = bf16_of(l0) | (bf16_of(l1) << 16);
        }
    } else {
        int i = (b - PRE_ZB - PRE_WB) * 256 + threadIdx.x;
        if (i >= N_NODES) return;
        int g = gid[i];
        if (i == 0) {
            for (int x = 0; x <= g; ++x) g_start[x] = 0;
        } else {
            int gp = gid[i - 1];
            for (int x = gp + 1; x <= g; ++x) g_start[x] = i;
        }
        if (i == N_NODES - 1) {
            for (int x = g + 1; x <= N_GRAPHS; ++x) g_start[x] = N_NODES;
        }
    }
}

// ELL build: deg[dst]++ slots, ell[dst*ELL_W + slot] = src  (replaces hist+scan+fill)
__global__ __launch_bounds__(256) void ellfill_kernel(const int* __restrict__ src,
                                                      const int* __restrict__ dst,
                                                      int* __restrict__ deg,
                                                      int* __restrict__ ell, int nE) {
    int i = blockIdx.x * 256 + threadIdx.x;
    if (i < nE) {
        int d = dst[i];
        int slot = atomicAdd(&deg[d], 1);
        if (slot < ELL_W) ell[(size_t)d * ELL_W + slot] = src[i];
    }
}

// fp32 pairs -> packed bf16 u32
__global__ __launch_bounds__(256) void cvt_kernel(const float2* __restrict__ src,
                                                  unsigned int* __restrict__ dst, int n) {
    int i = blockIdx.x * 256 + threadIdx.x;
    if (i < n) {
        float2 v = src[i];
        dst[i] = pack_bf2(v.x, v.y);
    }
}

// aggbf[n][:] = bf16( sum over ELL edges of Hbf[src][:] )  (fp32 accumulate)
// 2 nodes/wave (uint2 x 32 lanes), unroll x8 (16 row-streams/wave), full occupancy
__global__ __launch_bounds__(256) void aggregate_kernel(const unsigned int* __restrict__ Hbf,
                                                        const int* __restrict__ deg,
                                                        const int* __restrict__ ell,
                                                        unsigned int* __restrict__ aggbf,
                                                        int nN) {
    int wid  = (blockIdx.x * 256 + threadIdx.x) >> 6;
    int lane = threadIdx.x & 63;
    int half = lane >> 5;
    int l4   = lane & 31;
    int node = wid * 2 + half;
    if (node >= nN) return;
    int dg = deg[node];
    if (dg > ELL_W) dg = ELL_W;
    const int* ep = ell + (size_t)node * ELL_W;
    const uint2* H2 = (const uint2*)Hbf;
    float4 a0 = make_float4(0.f, 0.f, 0.f, 0.f);
    float4 a1 = make_float4(0.f, 0.f, 0.f, 0.f);
    float4 a2 = make_float4(0.f, 0.f, 0.f, 0.f);
    float4 a3 = make_float4(0.f, 0.f, 0.f, 0.f);
#define ACCUM(AX, V)                                                        \
    AX.x += __uint_as_float((V).x << 16);                                   \
    AX.y += __uint_as_float((V).x & 0xffff0000u);                           \
    AX.z += __uint_as_float((V).y << 16);                                   \
    AX.w += __uint_as_float((V).y & 0xffff0000u);
    int e = 0;
    for (; e + 7 < dg; e += 8) {
        int s0 = ep[e],     s1 = ep[e + 1], s2 = ep[e + 2], s3 = ep[e + 3];
        int s4 = ep[e + 4], s5 = ep[e + 5], s6 = ep[e + 6], s7 = ep[e + 7];
        uint2 v0 = H2[(size_t)s0 * 32 + l4];
        uint2 v1 = H2[(size_t)s1 * 32 + l4];
        uint2 v2 = H2[(size_t)s2 * 32 + l4];
        uint2 v3 = H2[(size_t)s3 * 32 + l4];
        uint2 v4 = H2[(size_t)s4 * 32 + l4];
        uint2 v5 = H2[(size_t)s5 * 32 + l4];
        uint2 v6 = H2[(size_t)s6 * 32 + l4];
        uint2 v7 = H2[(size_t)s7 * 32 + l4];
        ACCUM(a0, v0) ACCUM(a1, v1) ACCUM(a2, v2) ACCUM(a3, v3)
        ACCUM(a0, v4) ACCUM(a1, v5) ACCUM(a2, v6) ACCUM(a3, v7)
    }
    for (; e + 3 < dg; e += 4) {
        int s0 = ep[e], s1 = ep[e + 1], s2 = ep[e + 2], s3 = ep[e + 3];
        uint2 v0 = H2[(size_t)s0 * 32 + l4];
        uint2 v1 = H2[(size_t)s1 * 32 + l4];
        uint2 v2 = H2[(size_t)s2 * 32 + l4];
        uint2 v3 = H2[(size_t)s3 * 32 + l4];
        ACCUM(a0, v0) ACCUM(a1, v1) ACCUM(a2, v2) ACCUM(a3, v3)
    }
    for (; e < dg; ++e) {
        uint2 v0 = H2[(size_t)ep[e] * 32 + l4];
        ACCUM(a0, v0)
    }
#undef ACCUM
    a0.x += a1.x; a0.y += a1.y; a0.z += a1.z; a0.w += a1.w;
    a2.x += a3.x; a2.y += a3.y; a2.z += a3.z; a2.w += a3.w;
    a0.x += a2.x; a0.y += a2.y; a0.z += a2.z; a0.w += a2.w;
    uint2 o;
    o.x = pack_bf2(a0.x, a0.y);
    o.y = pack_bf2(a0.z, a0.w);
    ((uint2*)aggbf)[(size_t)node * 32 + l4] = o;
}

// dense MFMA GEMM for the embedding layer; writes H (fp32) and Hbf (bf16 ushorts)
__global__ __launch_bounds__(256) void gemm_mfma_embed(
    const uint4* __restrict__ Abf,
    const unsigned int* __restrict__ Wmat,
    const float* __restrict__ bias,
    float* __restrict__ Z, unsigned int* __restrict__ hbf, int nRows)
{
    __shared__ unsigned int As[64 * 64];
    int tid = threadIdx.x;
    int w  = tid >> 6;
    int l  = tid & 63;
    int q  = l >> 4;
    int ri = l & 15;
    int r0 = blockIdx.x * 64;

    short8 bfrag[2][2][4];
    const uint4* W4 = (const uint4*)Wmat;
#pragma unroll
    for (int p = 0; p < 2; ++p)
#pragma unroll
        for (int ct2 = 0; ct2 < 2; ++ct2) {
            int c = (w * 2 + ct2) * 16 + ri;
#pragma unroll
            for (int kc = 0; kc < 4; ++kc) {
                uint4 t = W4[p * 2048 + c * 16 + kc * 4 + q];
                bfrag[p][ct2][kc] = *(short8*)&t;
            }
        }

#pragma unroll
    for (int it = 0; it < 4; ++it) {
        int e = tid + it * 256;
        int r = e >> 4, g = e & 15;
        int gr = r0 + r;
        if (gr >= nRows) gr = nRows - 1;
        uint4 v = Abf[(size_t)gr * 16 + g];
        *(uint4*)&As[r * 64 + ((g ^ (r & 7)) << 2)] = v;
    }
    __syncthreads();

    f32x4 zero4 = {0.f, 0.f, 0.f, 0.f};
    f32x4 acc[4][2];
#pragma unroll
    for (int rt = 0; rt < 4; ++rt)
#pragma unroll
        for (int ct2 = 0; ct2 < 2; ++ct2) acc[rt][ct2] = zero4;

#pragma unroll
    for (int kc = 0; kc < 4; ++kc)
#pragma unroll
        for (int rt = 0; rt < 4; ++rt) {
            int row = rt * 16 + ri;
            short8 af = *(const short8*)&As[row * 64 + (((kc * 4 + q) ^ (ri & 7)) << 2)];
#pragma unroll
            for (int ct2 = 0; ct2 < 2; ++ct2) {
                acc[rt][ct2] = __builtin_amdgcn_mfma_f32_16x16x32_bf16(
                    af, bfrag[0][ct2][kc], acc[rt][ct2], 0, 0, 0);
                acc[rt][ct2] = __builtin_amdgcn_mfma_f32_16x16x32_bf16(
                    af, bfrag[1][ct2][kc], acc[rt][ct2], 0, 0, 0);
            }
        }

    unsigned short* hb = (unsigned short*)hbf;
#pragma unroll
    for (int ct2 = 0; ct2 < 2; ++ct2) {
        int col = (w * 2 + ct2) * 16 + ri;
        float bb = bias[col];
#pragma unroll
        for (int rt = 0; rt < 4; ++rt)
#pragma unroll
            for (int reg = 0; reg < 4; ++reg) {
                int row = r0 + rt * 16 + q * 4 + reg;
                if (row < nRows) {
                    float v = acc[rt][ct2][reg] + bb;
                    Z[(size_t)row * 128 + col] = v;
                    hb[(size_t)row * 128 + col] = (unsigned short)bf16_of(v);
                }
            }
    }
}

// dense MFMA GEMM (layer): A = aggbf, epilogue snorm + replica colsum
__global__ __launch_bounds__(256) void gemm_mfma_layer(
    const uint4* __restrict__ Abf,
    const unsigned int* __restrict__ Wmat,
    const float* __restrict__ bias, const float* __restrict__ snorm,
    float* __restrict__ Z, float* __restrict__ colsum, int nRows)
{
    __shared__ unsigned int As[64 * 64];
    int tid = threadIdx.x;
    int w  = tid >> 6;
    int l  = tid & 63;
    int q  = l >> 4;
    int ri = l & 15;
    int r0 = blockIdx.x * 64;

    short8 bfrag[2][2][4];
    const uint4* W4 = (const uint4*)Wmat;
#pragma unroll
    for (int p = 0; p < 2; ++p)
#pragma unroll
        for (int ct2 = 0; ct2 < 2; ++ct2) {
            int c = (w * 2 + ct2) * 16 + ri;
#pragma unroll
            for (int kc = 0; kc < 4; ++kc) {
                uint4 t = W4[p * 2048 + c * 16 + kc * 4 + q];
                bfrag[p][ct2][kc] = *(short8*)&t;
            }
        }

#pragma unroll
    for (int it = 0; it < 4; ++it) {
        int e = tid + it * 256;
        int r = e >> 4, g = e & 15;
        int gr = r0 + r;
        if (gr >= nRows) gr = nRows - 1;
        uint4 v = Abf[(size_t)gr * 16 + g];
        *(uint4*)&As[r * 64 + ((g ^ (r & 7)) << 2)] = v;
    }
    __syncthreads();

    f32x4 zero4 = {0.f, 0.f, 0.f, 0.f};
    f32x4 acc[4][2];
#pragma unroll
    for (int rt = 0; rt < 4; ++rt)
#pragma unroll
        for (int ct2 = 0; ct2 < 2; ++ct2) acc[rt][ct2] = zero4;

#pragma unroll
    for (int kc = 0; kc < 4; ++kc)
#pragma unroll
        for (int rt = 0; rt < 4; ++rt) {
            int row = rt * 16 + ri;
            short8 af = *(const short8*)&As[row * 64 + (((kc * 4 + q) ^ (ri & 7)) << 2)];
#pragma unroll
            for (int ct2 = 0; ct2 < 2; ++ct2) {
                acc[rt][ct2] = __builtin_amdgcn_mfma_f32_16x16x32_bf16(
                    af, bfrag[0][ct2][kc], acc[rt][ct2], 0, 0, 0);
                acc[rt][ct2] = __builtin_amdgcn_mfma_f32_16x16x32_bf16(
                    af, bfrag[1][ct2][kc], acc[rt][ct2], 0, 0, 0);
            }
        }

    float csv[2] = {0.f, 0.f}, cqv[2] = {0.f, 0.f};
#pragma unroll
    for (int ct2 = 0; ct2 < 2; ++ct2) {
        int col = (w * 2 + ct2) * 16 + ri;
        float bb = bias[col];
#pragma unroll
        for (int rt = 0; rt < 4; ++rt)
#pragma unroll
            for (int reg = 0; reg < 4; ++reg) {
                int row = r0 + rt * 16 + q * 4 + reg;
                if (row < nRows) {
                    float sn = snorm[row];
                    float v = (acc[rt][ct2][reg] + bb) * sn;
                    Z[(size_t)row * 128 + col] = v;
                    csv[ct2] += v;
                    cqv[ct2] += v * v;
                }
            }
    }
    {
        float* cdst = colsum + ((blockIdx.x & (NREP - 1)) << 8);
#pragma unroll
        for (int ct2 = 0; ct2 < 2; ++ct2) {
            float s  = csv[ct2], sq = cqv[ct2];
            s  += __shfl_xor(s, 16);  s  += __shfl_xor(s, 32);
            sq += __shfl_xor(sq, 16); sq += __shfl_xor(sq, 32);
            if (q == 0) {
                int col = (w * 2 + ct2) * 16 + ri;
                atomicAdd(&cdst[col], s);
                atomicAdd(&cdst[128 + col], sq);
            }
        }
    }
}

// fold NREP replica banks -> final csum[256] for one layer
__global__ __launch_bounds__(256) void bnred_kernel(const float* __restrict__ rep,
                                                    float* __restrict__ outp) {
    int t = threadIdx.x;
    float s = 0.f;
#pragma unroll
    for (int r = 0; r < NREP; ++r) s += rep[r * 256 + t];
    outp[t] = s;
}

// H += relu(BN(Z)); also emit bf16 H copy for the next layer's gather
__global__ __launch_bounds__(256) void apply_kernel(const float* __restrict__ Z,
                                                    const float* __restrict__ csum,
                                                    const float* __restrict__ gamma,
                                                    const float* __restrict__ beta,
                                                    float* __restrict__ H,
                                                    unsigned int* __restrict__ hbf,
                                                    int n4, int layer) {
    int i = blockIdx.x * 256 + threadIdx.x;
    if (i >= n4) return;
    int c4 = i & 31;
    const float invN = 1.0f / (float)N_NODES;
    float4 s  = ((const float4*)(csum  + layer * 256))[c4];
    float4 q  = ((const float4*)(csum  + layer * 256 + 128))[c4];
    float4 g  = ((const float4*)(gamma + layer * 128))[c4];
    float4 be = ((const float4*)(beta  + layer * 128))[c4];
    float4 z = ((const float4*)Z)[i];
    float4 h = ((float4*)H)[i];
    float mu, var, sc, sh;
    mu = s.x * invN; var = q.x * invN - mu * mu; sc = g.x * rsqrtf(var + BN_EPS); sh = be.x - mu * sc;
    h.x += fmaxf(z.x * sc + sh, 0.f);
    mu = s.y * invN; var = q.y * invN - mu * mu; sc = g.y * rsqrtf(var + BN_EPS); sh = be.y - mu * sc;
    h.y += fmaxf(z.y * sc + sh, 0.f);
    mu = s.z * invN; var = q.z * invN - mu * mu; sc = g.z * rsqrtf(var + BN_EPS); sh = be.z - mu * sc;
    h.z += fmaxf(z.z * sc + sh, 0.f);
    mu = s.w * invN; var = q.w * invN - mu * mu; sc = g.w * rsqrtf(var + BN_EPS); sh = be.w - mu * sc;
    h.w += fmaxf(z.w * sc + sh, 0.f);
    ((float4*)H)[i] = h;
    hbf[i * 2]     = pack_bf2(h.x, h.y);
    hbf[i * 2 + 1] = pack_bf2(h.z, h.w);
}

// dense per-graph reduction using sorted-gid boundaries (fp32 H)
__global__ __launch_bounds__(256) void readout2_kernel(const float* __restrict__ H,
                                                       const int* __restrict__ g_start,
                                                       float* __restrict__ sums) {
    int g     = blockIdx.x / RSPLIT;
    int chunk = blockIdx.x % RSPLIT;
    int beg = g_start[g], end = g_start[g + 1];
    int col  = threadIdx.x & 127;
    int half = threadIdx.x >> 7;
    float acc = 0.f;
    for (int r = beg + chunk * 2 + half; r < end; r += RSPLIT * 2) {
        acc += H[(size_t)r * 128 + col];
    }
    if (acc != 0.f || half == 0)
        atomicAdd(&sums[g * 128 + col], acc);
}

__global__ __launch_bounds__(128) void final_kernel(const float* __restrict__ sums,
                                                    const int* __restrict__ g_start,
                                                    const float* __restrict__ roW,
                                                    const float* __restrict__ rob,
                                                    float* __restrict__ out) {
    __shared__ float row[128];
    int g = blockIdx.x;
    int t = threadIdx.x;
    float c = fmaxf((float)(g_start[g + 1] - g_start[g]), 1.0f);
    row[t] = sums[g * 128 + t] / c;
    __syncthreads();
    if (t < N_CLASSES) {
        float s = rob[t];
        for (int k = 0; k < 128; ++k) s += row[k] * roW[t * 128 + k];
        out[g * N_CLASSES + t] = s;
    }
}

extern "C" void kernel_launch(void* const* d_in, const int* in_sizes, int n_in,
                              void* d_out, int out_size, void* d_ws, size_t ws_size,
                              hipStream_t stream) {
    const float* h0      = (const float*)d_in[0];
    const float* snorm   = (const float*)d_in[1];
    const int*   src     = (const int*)d_in[2];
    const int*   dst     = (const int*)d_in[3];
    const int*   gid     = (const int*)d_in[4];
    const float* embedW  = (const float*)d_in[5];
    const float* embedM  = (const float*)d_in[6];
    const float* embedB  = (const float*)d_in[7];
    const float* layerW  = (const float*)d_in[8];
    const float* layerM  = (const float*)d_in[9];
    const float* layerB  = (const float*)d_in[10];
    const float* gamma   = (const float*)d_in[11];
    const float* beta    = (const float*)d_in[12];
    const float* roW     = (const float*)d_in[13];
    const float* rob     = (const float*)d_in[14];
    float* out = (float*)d_out;

    float* ws   = (float*)d_ws;
    unsigned int* Wbf = (unsigned int*)(ws + OFF_WMT);
    float* H    = ws + OFF_H;
    float* Z    = ws + OFF_Z;
    unsigned int* h0bf  = (unsigned int*)(ws + OFF_H0BF);
    unsigned int* aggbf = (unsigned int*)(ws + OFF_AGGBF);
    float* csumr = ws + OFF_CSUMR;
    float* csumf = ws + OFF_CSUMF;
    float* sums = ws + OFF_SUMS;
    int*   deg  = (int*)(ws + OFF_DEG);
    int*   ell  = (int*)(ws + OFF_ELL);
    int*   gst  = (int*)(ws + OFF_GST);
    unsigned int* Hbf = (unsigned int*)(ws + OFF_HBF);

    // preamble: zero (csumr/sums/deg) | W->bf16 split-pair | bounds
    preamble_kernel<<<PRE_ZB + PRE_WB + PRE_BB, 256, 0, stream>>>(
        (int*)(ws + OFF_ZERO), embedW, embedM, layerW, layerM, Wbf, gid, gst);
    // ELL edge lists (1 launch, replaces hist+scan x3+fill)
    ellfill_kernel<<<(N_EDGES + 255) / 256, 256, 0, stream>>>(src, dst, deg, ell, N_EDGES);

    // h0 -> bf16, embed GEMM (MFMA) -> H fp32 + Hbf bf16 (inline)
    cvt_kernel<<<CVT_GRID, 256, 0, stream>>>((const float2*)h0, h0bf, CVT_N);
    gemm_mfma_embed<<<GEMM_GRID, 256, 0, stream>>>((const uint4*)h0bf, Wbf, embedB,
                                                   H, Hbf, N_NODES);

    const int agg_grid = (N_NODES / 2 + 3) / 4;
    for (int l = 0; l < N_LAYERS; ++l) {
        aggregate_kernel<<<agg_grid, 256, 0, stream>>>(Hbf, deg, ell, aggbf, N_NODES);
        gemm_mfma_layer<<<GEMM_GRID, 256, 0, stream>>>((const uint4*)aggbf,
                                                       Wbf + (1 + l) * 16384,
                                                       layerB + l * 128, snorm,
                                                       Z, csumr + l * (NREP * 256), N_NODES);
        bnred_kernel<<<1, 256, 0, stream>>>(csumr + l * (NREP * 256), csumf + l * 256);
        apply_kernel<<<(N_NODES * HID / 4) / 256, 256, 0, stream>>>(
            Z, csumf, gamma, beta, H, Hbf, N_NODES * HID / 4, l);
    }

    readout2_kernel<<<N_GRAPHS * RSPLIT, 256, 0, stream>>>(H, gst, sums);
    final_kernel<<<N_GRAPHS, 128, 0, stream>>>(sums, gst, roW, rob, out);
}